// Round 5
// baseline (253.796 us; speedup 1.0000x reference)
//
#include <hip/hip_runtime.h>
#include <hip/hip_bf16.h>

#define Bn 8
#define Nn 4096
#define Cn 1024
#define Dn 512
#define Mn 64

typedef __hip_bfloat16 bf16;
typedef __attribute__((ext_vector_type(8))) short short8;
typedef __attribute__((ext_vector_type(4))) short short4x;
typedef __attribute__((ext_vector_type(4))) float f32x4;

#define MFMA16(a, b, c) __builtin_amdgcn_mfma_f32_16x16x32_bf16((a), (b), (c), 0, 0, 0)

__device__ inline short bfbits(float f) {
  union { bf16 b; short s; } u;
  u.b = __float2bfloat16(f);
  return u.s;
}

__device__ inline short8 pack8(const float4& a, const float4& b) {
  short8 s;
  s[0] = bfbits(a.x); s[1] = bfbits(a.y); s[2] = bfbits(a.z); s[3] = bfbits(a.w);
  s[4] = bfbits(b.x); s[5] = bfbits(b.y); s[6] = bfbits(b.z); s[7] = bfbits(b.w);
  return s;
}

// ---------------------------------------------------------------------------
// K0: V[m][c] = sum_d av[m][d]*W[d][c]  (bf16 hi+lo);  c0[m] = av[m,:].bias
// grid (Mn, Cn/64) = 1024 blocks, block 256 = 64c x 4 d-groups
// ---------------------------------------------------------------------------
__global__ __launch_bounds__(256) void prep_kernel(
    const float* __restrict__ W, const float* __restrict__ bias,
    const float* __restrict__ av, bf16* __restrict__ Vhi,
    bf16* __restrict__ Vlo, float* __restrict__ c0) {
  const int m = blockIdx.x;
  const int t = threadIdx.x;
  const int cl = t & 63, dg = t >> 6;
  const int c = blockIdx.y * 64 + cl;
  const float* wp = W + (size_t)(dg * 128) * Cn + c;
  const float* ap = av + m * Dn + dg * 128;
  float a0 = 0.f, a1 = 0.f, a2 = 0.f, a3 = 0.f;
#pragma unroll 8
  for (int i = 0; i < 128; i += 4) {
    a0 = fmaf(ap[i + 0], wp[(size_t)(i + 0) * Cn], a0);
    a1 = fmaf(ap[i + 1], wp[(size_t)(i + 1) * Cn], a1);
    a2 = fmaf(ap[i + 2], wp[(size_t)(i + 2) * Cn], a2);
    a3 = fmaf(ap[i + 3], wp[(size_t)(i + 3) * Cn], a3);
  }
  __shared__ float red[256];
  red[t] = (a0 + a1) + (a2 + a3);
  __syncthreads();
  const float v = red[cl] + red[cl + 64] + red[cl + 128] + red[cl + 192];
  if (dg == 0) {
    const bf16 hi = __float2bfloat16(v);
    Vhi[m * Cn + c] = hi;
    Vlo[m * Cn + c] = __float2bfloat16(v - __bfloat162float(hi));
  }
  if (blockIdx.y == 0) {
    __syncthreads();
    red[t] = av[m * Dn + t] * bias[t] + av[m * Dn + t + 256] * bias[t + 256];
    __syncthreads();
    if (t < 64) {
      float s = red[t] + red[t + 64] + red[t + 128] + red[t + 192];
#pragma unroll
      for (int off = 32; off > 0; off >>= 1) s += __shfl_down(s, off);
      if (t == 0) c0[m] = s;
    }
  }
}

// ---------------------------------------------------------------------------
// K1: logits[b][m][n] = x[b][n][:].V[m][:] + c0[m]
// Software pipeline, 1 barrier/chunk (K-chunk 64), double-buffered V in LDS,
// x direct global->reg (lane = one n-row, frags k-contiguous).  Epilogue
// transposes accs through LDS for 256B-contiguous logits stores.
// grid (Nn/64, Bn) = 512, block 256; LDS 36.9 KB -> 2 blocks/CU (grid-bound).
// ---------------------------------------------------------------------------
__global__ __launch_bounds__(256) void logits_kernel(
    const float* __restrict__ x, const bf16* __restrict__ Vhi,
    const bf16* __restrict__ Vlo, const float* __restrict__ c0,
    float* __restrict__ logits) {
  const int n0 = blockIdx.x * 64;
  const int b = blockIdx.y;
  const int t = threadIdx.x;
  __shared__ short Vs[2][2][64][72];  // [buf][hi/lo][m][k]
  const int w = t >> 6, lane = t & 63, lr = lane & 15, q = lane >> 4;

  // V staging: round j<2: unit u=t+256j: row=u>>3 (0..63), seg=(u&7)*8 shorts
  int vr[2], vc[2];
  const bf16 *hsrc[2], *lsrc[2];
#pragma unroll
  for (int j = 0; j < 2; ++j) {
    const int u = t + 256 * j;
    vr[j] = u >> 3;
    vc[j] = (u & 7) * 8;
    hsrc[j] = Vhi + vr[j] * Cn + vc[j];
    lsrc[j] = Vlo + vr[j] * Cn + vc[j];
  }
  const float* xrow = x + (size_t)(b * Nn + n0 + w * 16 + lr) * Cn + q * 8;

  f32x4 acc[4];
#pragma unroll
  for (int i = 0; i < 4; ++i) acc[i] = (f32x4){0.f, 0.f, 0.f, 0.f};

  short8 vh[2], vl[2];
  float4 xs0, xs1, xs2, xs3;

  // prologue: V(0)->LDS[0]; V(1)->regs; x(0)->regs
#pragma unroll
  for (int j = 0; j < 2; ++j) {
    vh[j] = *(const short8*)(hsrc[j]);
    vl[j] = *(const short8*)(lsrc[j]);
  }
  xs0 = *(const float4*)(xrow);
  xs1 = *(const float4*)(xrow + 4);
  xs2 = *(const float4*)(xrow + 32);
  xs3 = *(const float4*)(xrow + 36);
#pragma unroll
  for (int j = 0; j < 2; ++j) {
    *(short8*)&Vs[0][0][vr[j]][vc[j]] = vh[j];
    *(short8*)&Vs[0][1][vr[j]][vc[j]] = vl[j];
  }
#pragma unroll
  for (int j = 0; j < 2; ++j) {
    vh[j] = *(const short8*)(hsrc[j] + 64);
    vl[j] = *(const short8*)(lsrc[j] + 64);
  }
  __syncthreads();

#pragma unroll
  for (int kc = 0; kc < 16; ++kc) {
    const int buf = kc & 1;
    // consume x(kc) -> A-frags, then reissue x(kc+1)
    const short8 a0 = pack8(xs0, xs1);
    const short8 a1 = pack8(xs2, xs3);
    if (kc < 15) {
      const int k1 = (kc + 1) * 64;
      xs0 = *(const float4*)(xrow + k1);
      xs1 = *(const float4*)(xrow + k1 + 4);
      xs2 = *(const float4*)(xrow + k1 + 32);
      xs3 = *(const float4*)(xrow + k1 + 36);
    }
    // write V(kc+1) regs -> LDS[buf^1], reissue V(kc+2)
    if (kc < 15) {
#pragma unroll
      for (int j = 0; j < 2; ++j) {
        *(short8*)&Vs[buf ^ 1][0][vr[j]][vc[j]] = vh[j];
        *(short8*)&Vs[buf ^ 1][1][vr[j]][vc[j]] = vl[j];
      }
    }
    if (kc < 14) {
      const int k2 = (kc + 2) * 64;
#pragma unroll
      for (int j = 0; j < 2; ++j) {
        vh[j] = *(const short8*)(hsrc[j] + k2);
        vl[j] = *(const short8*)(lsrc[j] + k2);
      }
    }
    // MFMA from LDS[buf]
#pragma unroll
    for (int kk2 = 0; kk2 < 2; ++kk2) {
      const short8 a = kk2 ? a1 : a0;
      const int ko = kk2 * 32 + q * 8;
#pragma unroll
      for (int mt = 0; mt < 4; ++mt) {
        acc[mt] = MFMA16(a, *(const short8*)&Vs[buf][0][mt * 16 + lr][ko], acc[mt]);
        acc[mt] = MFMA16(a, *(const short8*)&Vs[buf][1][mt * 16 + lr][ko], acc[mt]);
      }
    }
    __syncthreads();
  }

  // epilogue: accs -> LDS (transpose) -> coalesced 256B stores
  float (*LT)[68] = reinterpret_cast<float(*)[68]>(&Vs[0][0][0][0]);
#pragma unroll
  for (int mt = 0; mt < 4; ++mt) {
    const int m = mt * 16 + lr;
    const float bb = c0[m];
    f32x4 o = acc[mt];
    o[0] += bb; o[1] += bb; o[2] += bb; o[3] += bb;
    *(f32x4*)&LT[m][w * 16 + q * 4] = o;
  }
  __syncthreads();
  {
    const int mr = t >> 2, seg = (t & 3) * 16;
    const float* srcL = &LT[mr][seg];
    float* dst = logits + (size_t)(b * Mn + mr) * Nn + n0 + seg;
#pragma unroll
    for (int i = 0; i < 4; ++i) *(float4*)(dst + 4 * i) = *(const float4*)(srcL + 4 * i);
  }
}

// ---------------------------------------------------------------------------
// K2: softmax over N per (b,m) row; bf16 weights out. grid Bn*Mn, block 256
// ---------------------------------------------------------------------------
__global__ __launch_bounds__(256) void softmax_kernel(
    const float* __restrict__ logits, bf16* __restrict__ wgt) {
  const int row = blockIdx.x;
  const int t = threadIdx.x;
  const float* L = logits + (size_t)row * Nn;
  float v[16];
  float mx = -3.4e38f;
#pragma unroll
  for (int i = 0; i < 16; ++i) {
    v[i] = L[t + 256 * i];
    mx = fmaxf(mx, v[i]);
  }
#pragma unroll
  for (int off = 32; off > 0; off >>= 1) mx = fmaxf(mx, __shfl_down(mx, off));
  __shared__ float sred[4];
  if ((t & 63) == 0) sred[t >> 6] = mx;
  __syncthreads();
  mx = fmaxf(fmaxf(sred[0], sred[1]), fmaxf(sred[2], sred[3]));
  float sum = 0.f;
#pragma unroll
  for (int i = 0; i < 16; ++i) {
    v[i] = __expf(v[i] - mx);
    sum += v[i];
  }
#pragma unroll
  for (int off = 32; off > 0; off >>= 1) sum += __shfl_down(sum, off);
  __syncthreads();
  if ((t & 63) == 0) sred[t >> 6] = sum;
  __syncthreads();
  const float inv = 1.f / (sred[0] + sred[1] + sred[2] + sred[3]);
#pragma unroll
  for (int i = 0; i < 16; ++i)
    wgt[(size_t)row * Nn + t + 256 * i] = __float2bfloat16(v[i] * inv);
}

// ---------------------------------------------------------------------------
// K3: part[ks][b][m][c] = sum_{k-quarter} wgt[b][m][k]*x[b][k][c]
// Same pipeline: K-chunk 64, double-buffered swizzled x-transpose in LDS,
// wgt A-frags direct global->reg, 1 barrier/chunk.
// grid (Cn/64, Bn, 4) = 512, block 256; LDS 18.4 KB.
// ---------------------------------------------------------------------------
__global__ __launch_bounds__(256) void pool_kernel(
    const float* __restrict__ x, const bf16* __restrict__ wgt,
    float* __restrict__ part) {
  const int cbase = blockIdx.x * 64;
  const int b = blockIdx.y;
  const int ks = blockIdx.z;
  const int t = threadIdx.x;
  __shared__ short XT[2][64][72];  // [buf][c][k^swz]
  const int w = t >> 6, lane = t & 63, lr = lane & 15, q = lane >> 4;
  const int mh = (w & 1) * 32, ch = (w >> 1) * 32;
  f32x4 acc[2][2];
#pragma unroll
  for (int i = 0; i < 2; ++i)
#pragma unroll
    for (int j = 0; j < 2; ++j) acc[i][j] = (f32x4){0.f, 0.f, 0.f, 0.f};

  const int h = t & 15, g = t >> 4;
  const int swz = 8 * (h & 7);
  const int swzr0 = 8 * (((ch + lr) >> 2) & 7);
  const int swzr1 = 8 * (((ch + 16 + lr) >> 2) & 7);
  const int kbase = ks * (Nn / 4);
  const float* xsrc = x + (size_t)b * Nn * Cn + (size_t)(kbase + 4 * g) * Cn + cbase + 4 * h;
  const bf16* wr0 = wgt + (size_t)(b * Mn + mh + lr) * Nn + kbase + q * 8;
  const bf16* wr1 = wr0 + (size_t)16 * Nn;

  float4 p0, p1, p2, p3;
  short8 aw0, aw1, aw2, aw3;

  // prologue: x(0)->regs->LDS[0]; x(1)->regs; wgt(0)->regs
  p0 = *(const float4*)(xsrc);
  p1 = *(const float4*)(xsrc + Cn);
  p2 = *(const float4*)(xsrc + 2 * Cn);
  p3 = *(const float4*)(xsrc + 3 * Cn);
  aw0 = *(const short8*)(wr0);
  aw1 = *(const short8*)(wr0 + 32);
  aw2 = *(const short8*)(wr1);
  aw3 = *(const short8*)(wr1 + 32);
  {
    const int kof = (4 * g) ^ swz;
    short4x v0, v1, v2, v3;
    v0[0] = bfbits(p0.x); v0[1] = bfbits(p1.x); v0[2] = bfbits(p2.x); v0[3] = bfbits(p3.x);
    v1[0] = bfbits(p0.y); v1[1] = bfbits(p1.y); v1[2] = bfbits(p2.y); v1[3] = bfbits(p3.y);
    v2[0] = bfbits(p0.z); v2[1] = bfbits(p1.z); v2[2] = bfbits(p2.z); v2[3] = bfbits(p3.z);
    v3[0] = bfbits(p0.w); v3[1] = bfbits(p1.w); v3[2] = bfbits(p2.w); v3[3] = bfbits(p3.w);
    *(short4x*)&XT[0][4 * h + 0][kof] = v0;
    *(short4x*)&XT[0][4 * h + 1][kof] = v1;
    *(short4x*)&XT[0][4 * h + 2][kof] = v2;
    *(short4x*)&XT[0][4 * h + 3][kof] = v3;
  }
  p0 = *(const float4*)(xsrc + (size_t)64 * Cn);
  p1 = *(const float4*)(xsrc + (size_t)65 * Cn);
  p2 = *(const float4*)(xsrc + (size_t)66 * Cn);
  p3 = *(const float4*)(xsrc + (size_t)67 * Cn);
  __syncthreads();

#pragma unroll 4
  for (int kc = 0; kc < 16; ++kc) {
    const int buf = kc & 1;
    // consume wgt(kc), reissue wgt(kc+1)
    const short8 a00 = aw0, a01 = aw1, a10 = aw2, a11 = aw3;
    if (kc < 15) {
      const int k1 = (kc + 1) * 64;
      aw0 = *(const short8*)(wr0 + k1);
      aw1 = *(const short8*)(wr0 + k1 + 32);
      aw2 = *(const short8*)(wr1 + k1);
      aw3 = *(const short8*)(wr1 + k1 + 32);
    }
    // write x(kc+1) regs -> LDS[buf^1], reissue x(kc+2)
    if (kc < 15) {
      const int kof = (4 * g) ^ swz;
      short4x v0, v1, v2, v3;
      v0[0] = bfbits(p0.x); v0[1] = bfbits(p1.x); v0[2] = bfbits(p2.x); v0[3] = bfbits(p3.x);
      v1[0] = bfbits(p0.y); v1[1] = bfbits(p1.y); v1[2] = bfbits(p2.y); v1[3] = bfbits(p3.y);
      v2[0] = bfbits(p0.z); v2[1] = bfbits(p1.z); v2[2] = bfbits(p2.z); v2[3] = bfbits(p3.z);
      v3[0] = bfbits(p0.w); v3[1] = bfbits(p1.w); v3[2] = bfbits(p2.w); v3[3] = bfbits(p3.w);
      *(short4x*)&XT[buf ^ 1][4 * h + 0][kof] = v0;
      *(short4x*)&XT[buf ^ 1][4 * h + 1][kof] = v1;
      *(short4x*)&XT[buf ^ 1][4 * h + 2][kof] = v2;
      *(short4x*)&XT[buf ^ 1][4 * h + 3][kof] = v3;
    }
    if (kc < 14) {
      const size_t roff = (size_t)(kc + 2) * 64 * Cn;
      p0 = *(const float4*)(xsrc + roff);
      p1 = *(const float4*)(xsrc + roff + Cn);
      p2 = *(const float4*)(xsrc + roff + 2 * Cn);
      p3 = *(const float4*)(xsrc + roff + 3 * Cn);
    }
    // MFMA from LDS[buf]
#pragma unroll
    for (int kk2 = 0; kk2 < 2; ++kk2) {
      const int ko = kk2 * 32 + q * 8;
      const short8 b0 = *(const short8*)&XT[buf][ch + lr][ko ^ swzr0];
      const short8 b1 = *(const short8*)&XT[buf][ch + 16 + lr][ko ^ swzr1];
      const short8 aa = kk2 ? a01 : a00;
      const short8 ab = kk2 ? a11 : a10;
      acc[0][0] = MFMA16(aa, b0, acc[0][0]);
      acc[0][1] = MFMA16(aa, b1, acc[0][1]);
      acc[1][0] = MFMA16(ab, b0, acc[1][0]);
      acc[1][1] = MFMA16(ab, b1, acc[1][1]);
    }
    __syncthreads();
  }

  float* pout = part + ((size_t)ks * Bn + b) * Mn * Cn;
#pragma unroll
  for (int mi = 0; mi < 2; ++mi)
#pragma unroll
    for (int ci = 0; ci < 2; ++ci) {
      const int m = mh + mi * 16 + q * 4;
      const int c = cbase + ch + ci * 16 + lr;
#pragma unroll
      for (int reg = 0; reg < 4; ++reg)
        pout[(size_t)(m + reg) * Cn + c] = acc[mi][ci][reg];
    }
}

// ---------------------------------------------------------------------------
// K4: out = sum of 4 partials (float4).  grid 512, block 256
// ---------------------------------------------------------------------------
__global__ __launch_bounds__(256) void reduce_kernel(
    const float* __restrict__ part, float* __restrict__ out) {
  const int i = blockIdx.x * 256 + threadIdx.x;
  const float4* p = (const float4*)part;
  const int S4 = (Bn * Mn * Cn) / 4;
  const float4 v0 = p[i], v1 = p[i + S4], v2 = p[i + 2 * S4], v3 = p[i + 3 * S4];
  float4 o;
  o.x = (v0.x + v1.x) + (v2.x + v3.x);
  o.y = (v0.y + v1.y) + (v2.y + v3.y);
  o.z = (v0.z + v1.z) + (v2.z + v3.z);
  o.w = (v0.w + v1.w) + (v2.w + v3.w);
  ((float4*)out)[i] = o;
}

extern "C" void kernel_launch(void* const* d_in, const int* in_sizes, int n_in,
                              void* d_out, int out_size, void* d_ws, size_t ws_size,
                              hipStream_t stream) {
  const float* x = (const float*)d_in[0];
  const float* W = (const float*)d_in[1];
  const float* bias = (const float*)d_in[2];
  const float* av = (const float*)d_in[3];
  float* out = (float*)d_out;
  char* ws = (char*)d_ws;

  bf16* Vhi = (bf16*)(ws + 0);            // 131072 B
  bf16* Vlo = (bf16*)(ws + 131072);       // 131072 B
  float* c0 = (float*)(ws + 262144);      // 1024 B
  float* logits = (float*)(ws + 263168);  // 8388608 B
  bf16* wgt = (bf16*)(ws + 8651776);      // 4194304 B
  float* part = (float*)(ws + 12846080);  // 4 x 2097152 B  (total ~20.3 MB)

  prep_kernel<<<dim3(Mn, Cn / 64), 256, 0, stream>>>(W, bias, av, Vhi, Vlo, c0);
  logits_kernel<<<dim3(Nn / 64, Bn), 256, 0, stream>>>(x, Vhi, Vlo, c0, logits);
  softmax_kernel<<<Bn * Mn, 256, 0, stream>>>(logits, wgt);
  pool_kernel<<<dim3(Cn / 64, Bn, 4), 256, 0, stream>>>(x, wgt, part);
  reduce_kernel<<<(Bn * Mn * Cn) / 1024, 256, 0, stream>>>(part, out);
}